// Round 5
// baseline (2007.152 us; speedup 1.0000x reference)
//
#include <hip/hip_runtime.h>

#define N_NODES 100000
#define N_EDGES 600000
#define NODE_DIM 64
#define EDGE_DIM 32
#define HID 128
#define OUT_DIM 24

typedef short short8 __attribute__((ext_vector_type(8)));
typedef short short4v __attribute__((ext_vector_type(4)));
typedef float f32x4 __attribute__((ext_vector_type(4)));

#define MFMA16(a, b, c) __builtin_amdgcn_mfma_f32_16x16x32_bf16(a, b, c, 0, 0, 0)

__device__ inline unsigned short f2bf(float f) {
  unsigned u = __float_as_uint(f);
  u += 0x7FFFu + ((u >> 16) & 1u);
  return (unsigned short)(u >> 16);
}
__device__ inline float bf2f(unsigned short b) {
  return __uint_as_float(((unsigned)b) << 16);
}

// ---- prepped weight region layout (ushort units) ----
#define OFF_CW1T 0                        // cls w1^T bf16 [128][288]
#define OFF_CW2T 36864                    // cls w2^T bf16 [32 pad][128]
#define OFF_LAYER(c) (40960 + (c)*65536)  // per conv: w1t_hi,w1t_lo,w2t_hi,w2t_lo each [128][128]
#define OFF_EWF(c) (237568 + (c)*8192)    // per conv: ew B-frag hi[4096], lo[4096]
#define W_TOTAL 262144                    // 512 KB

__global__ __launch_bounds__(256) void prep_weights(
    const float* __restrict__ cw1, const float* __restrict__ cw2,
    const float* __restrict__ l0w1, const float* __restrict__ l0w2,
    const float* __restrict__ l1w1, const float* __restrict__ l1w2,
    const float* __restrict__ l2w1, const float* __restrict__ l2w2,
    const float* __restrict__ l0ew, const float* __restrict__ l1ew,
    const float* __restrict__ l2ew,
    unsigned short* __restrict__ wb) {
  int i = blockIdx.x * 256 + threadIdx.x;
  if (i < 36864) {                       // cls w1t[n][k] = cw1[k][n]
    int n = i / 288, k = i % 288;
    wb[OFF_CW1T + i] = f2bf(cw1[k * 128 + n]);
  }
  int j = i - 36864;
  if (j >= 0 && j < 4096) {              // cls w2t[n][k], n padded to 32
    int n = j / 128, k = j % 128;
    wb[OFF_CW2T + j] = f2bf(n < 24 ? cw2[k * 24 + n] : 0.f);
  }
  int t = i - 40960;
  if (t >= 0 && t < 3 * 32768) {         // conv w1/w2, split hi/lo
    int c = t / 32768, u = t % 32768;
    const float* w = (u < 16384) ? (c == 0 ? l0w1 : c == 1 ? l1w1 : l2w1)
                                 : (c == 0 ? l0w2 : c == 1 ? l1w2 : l2w2);
    int v = u & 16383;
    int n = v >> 7, k = v & 127;
    float val = w[k * 128 + n];
    unsigned short hi = f2bf(val);
    unsigned short lo = f2bf(val - bf2f(hi));
    int base = OFF_LAYER(c) + (u < 16384 ? 0 : 32768);
    wb[base + v] = hi;
    wb[base + 16384 + v] = lo;
  }
  int u2 = i - 139264;                   // ew B-fragments, split hi/lo
  if (u2 >= 0 && u2 < 3 * 4096) {
    int c = u2 / 4096, v = u2 % 4096;
    const float* ew = (c == 0 ? l0ew : c == 1 ? l1ew : l2ew);
    int jj = v & 7, lane = (v >> 3) & 63, nt = v >> 9;
    int n = nt * 16 + (lane & 15);
    int k = (lane >> 4) * 8 + jj;
    float val = ew[k * HID + n];
    unsigned short hi = f2bf(val);
    wb[OFF_EWF(c) + v] = hi;
    wb[OFF_EWF(c) + 4096 + v] = f2bf(val - bf2f(hi));
  }
}

// ================= lin1: h = x @ w + b  (K=64, fp32) =================
__global__ __launch_bounds__(256) void lin1_kernel(
    const float* __restrict__ x, const float* __restrict__ w,
    const float* __restrict__ b, float* __restrict__ h) {
  __shared__ float4 smem4[3072];
  float* sA = (float*)smem4;
  float* sB = (float*)smem4 + 4096;
  int tid = threadIdx.x;
  int tn = tid & 31, tm = tid >> 5;
  int mbase = blockIdx.x * 64;

  for (int i = tid; i < 1024; i += 256) {
    int m = i & 63, k4 = (i >> 6) << 2;
    int row = mbase + m; if (row >= N_NODES) row = N_NODES - 1;
    float4 v = *(const float4*)(x + (size_t)row * NODE_DIM + k4);
    sA[(k4 + 0) * 64 + m] = v.x; sA[(k4 + 1) * 64 + m] = v.y;
    sA[(k4 + 2) * 64 + m] = v.z; sA[(k4 + 3) * 64 + m] = v.w;
  }
  for (int i = tid; i < 2048; i += 256)
    *(float4*)&sB[i * 4] = ((const float4*)w)[i];
  __syncthreads();

  float acc[8][4] = {};
#pragma unroll 8
  for (int k = 0; k < 64; ++k) {
    float4 a0 = *(float4*)&sA[k * 64 + tm * 8];
    float4 a1 = *(float4*)&sA[k * 64 + tm * 8 + 4];
    float4 bv = *(float4*)&sB[k * 128 + tn * 4];
    float av[8] = {a0.x, a0.y, a0.z, a0.w, a1.x, a1.y, a1.z, a1.w};
    float bb[4] = {bv.x, bv.y, bv.z, bv.w};
#pragma unroll
    for (int i = 0; i < 8; ++i)
#pragma unroll
      for (int jj = 0; jj < 4; ++jj) acc[i][jj] = fmaf(av[i], bb[jj], acc[i][jj]);
  }
  float4 bv = *(const float4*)(b + tn * 4);
#pragma unroll
  for (int i = 0; i < 8; ++i) {
    int row = mbase + tm * 8 + i;
    if (row < N_NODES) {
      float4 o = {acc[i][0] + bv.x, acc[i][1] + bv.y, acc[i][2] + bv.z, acc[i][3] + bv.w};
      *(float4*)(h + (size_t)row * HID + tn * 4) = o;
    }
  }
}

// ======================= CSR build =======================
__global__ __launch_bounds__(256) void hist_kernel(
    const int* __restrict__ dst, int* __restrict__ counts) {
  int e = blockIdx.x * 256 + threadIdx.x;
  if (e < N_EDGES) atomicAdd(&counts[dst[e]], 1);
}

#define SCAN_BLK 98
__global__ __launch_bounds__(256) void scan_partial(
    const int* __restrict__ cnt, int* __restrict__ partial) {
  __shared__ int sdata[256];
  int b = blockIdx.x, t = threadIdx.x;
  int sum = 0;
  for (int i = t; i < 1024; i += 256) {
    int idx = b * 1024 + i;
    sum += (idx < N_NODES) ? cnt[idx] : 0;
  }
  sdata[t] = sum; __syncthreads();
  for (int s = 128; s > 0; s >>= 1) {
    if (t < s) sdata[t] += sdata[t + s];
    __syncthreads();
  }
  if (t == 0) partial[b] = sdata[0];
}

__global__ void scan_sums(const int* __restrict__ partial,
                          int* __restrict__ partialScan, int* __restrict__ rowptr) {
  if (threadIdx.x == 0) {
    int acc = 0;
    for (int i = 0; i < SCAN_BLK; ++i) { partialScan[i] = acc; acc += partial[i]; }
    rowptr[N_NODES] = acc;
  }
}

__global__ __launch_bounds__(256) void scan_final(
    const int* __restrict__ cnt, const int* __restrict__ partialScan,
    int* __restrict__ rowptr, int* __restrict__ cur) {
  __shared__ int sdata[256];
  int b = blockIdx.x, t = threadIdx.x;
  int i0 = b * 1024 + t * 4;
  int c[4]; int s = 0;
#pragma unroll
  for (int j = 0; j < 4; ++j) {
    c[j] = (i0 + j < N_NODES) ? cnt[i0 + j] : 0;
    s += c[j];
  }
  sdata[t] = s; __syncthreads();
  for (int d = 1; d < 256; d <<= 1) {
    int u = (t >= d) ? sdata[t - d] : 0;
    __syncthreads();
    sdata[t] += u;
    __syncthreads();
  }
  int off = sdata[t] - s + partialScan[b];
#pragma unroll
  for (int j = 0; j < 4; ++j) {
    int idx = i0 + j;
    if (idx < N_NODES) { rowptr[idx] = off; cur[idx] = off; off += c[j]; }
  }
}

__global__ __launch_bounds__(256) void scatter_kernel(
    const int* __restrict__ dst, int* __restrict__ cur, int* __restrict__ perm) {
  int e = blockIdx.x * 256 + threadIdx.x;
  if (e < N_EDGES) {
    int slot = atomicAdd(&cur[dst[e]], 1);
    perm[slot] = e;
  }
}

// ======== fused msg-GEMM (MFMA) + segmented reduce, 128 perm-slots/block ========
__global__ __launch_bounds__(256) void msg_agg_kernel(
    const float* __restrict__ h, const float* __restrict__ ea,
    const int* __restrict__ src, const int* __restrict__ dst,
    const int* __restrict__ perm,
    const unsigned short* __restrict__ ewf,  // B-frag hi[4096], lo[4096]
    const float* __restrict__ eb,
    float* __restrict__ agg) {
  __shared__ float msg[128 * 130];       // 66.6 KB (stride 130: conflict-free)
  __shared__ unsigned short aFrag[4096]; // 8 KB: A-fragments bf16
  __shared__ int s_e[128], s_src[128], s_node[128];
  int tid = threadIdx.x, lane = tid & 63, wave = tid >> 6;
  int wm = wave & 1, wn = wave >> 1;
  int p0 = blockIdx.x * 128;

  if (tid < 128) {
    int p = p0 + tid;
    int e = (p < N_EDGES) ? perm[p] : -1;
    s_e[tid] = e;
    s_src[tid] = (e >= 0) ? src[e] : 0;
    s_node[tid] = (e >= 0) ? dst[e] : -1;
  }
  __syncthreads();

  // stage A: edge m = tid>>1, k-half = tid&1 (16 of 32 k-dims)
  {
    int m = tid >> 1, half = tid & 1;
    int e = s_e[m];
    short8 v0 = {0,0,0,0,0,0,0,0}, v1 = v0;
    if (e >= 0) {
      const float4* ep = (const float4*)(ea + (size_t)e * EDGE_DIM + half * 16);
      float4 a = ep[0], b = ep[1], c = ep[2], d = ep[3];
      v0 = short8{(short)f2bf(a.x), (short)f2bf(a.y), (short)f2bf(a.z), (short)f2bf(a.w),
                  (short)f2bf(b.x), (short)f2bf(b.y), (short)f2bf(b.z), (short)f2bf(b.w)};
      v1 = short8{(short)f2bf(c.x), (short)f2bf(c.y), (short)f2bf(c.z), (short)f2bf(c.w),
                  (short)f2bf(d.x), (short)f2bf(d.y), (short)f2bf(d.z), (short)f2bf(d.w)};
    }
    int base = (m >> 4) * 64 + (m & 15);
    *(short8*)(aFrag + (base + (half * 2 + 0) * 16) * 8) = v0;
    *(short8*)(aFrag + (base + (half * 2 + 1) * 16) * 8) = v1;
  }
  __syncthreads();

  // MFMA: e_emb = ea_bf16 @ (ew_hi + ew_lo)
  f32x4 acc[4][4];
  {
    const f32x4 zf = {0.f, 0.f, 0.f, 0.f};
    short8 bh[4], bl[4], ah[4];
#pragma unroll
    for (int nt = 0; nt < 4; ++nt) {
      bh[nt] = *(const short8*)(ewf + ((wn * 4 + nt) * 64 + lane) * 8);
      bl[nt] = *(const short8*)(ewf + 4096 + ((wn * 4 + nt) * 64 + lane) * 8);
    }
#pragma unroll
    for (int mt = 0; mt < 4; ++mt)
      ah[mt] = *(short8*)(aFrag + ((wm * 4 + mt) * 64 + lane) * 8);
#pragma unroll
    for (int mt = 0; mt < 4; ++mt)
#pragma unroll
      for (int nt = 0; nt < 4; ++nt) {
        acc[mt][nt] = MFMA16(ah[mt], bh[nt], zf);
        acc[mt][nt] = MFMA16(ah[mt], bl[nt], acc[mt][nt]);
      }
  }
  // epilogue: msg = e_emb + eb  -> LDS
  {
    int q = lane >> 4, r = lane & 15;
#pragma unroll
    for (int nt = 0; nt < 4; ++nt) {
      int n = wn * 64 + nt * 16 + r;
      float ebv = eb[n];
#pragma unroll
      for (int mt = 0; mt < 4; ++mt) {
        int mb = (wm * 4 + mt) * 16 + q * 4;
#pragma unroll
        for (int i2 = 0; i2 < 4; ++i2)
          msg[(mb + i2) * 130 + n] = acc[mt][nt][i2] + ebv;
      }
    }
  }
  __syncthreads();

  // segmented reduce: thread d walks 128 slots; relu(h[src]+msg), sum by dst
  if (tid < 128) {
    int d = tid;
    float a = 0.f;
    int prev = -1;
    bool firstSeg = true;
#pragma unroll 2
    for (int sl = 0; sl < 128; ++sl) {
      int node = s_node[sl];
      if (node != prev) {
        if (prev >= 0) {
          if (firstSeg) atomicAdd(&agg[(size_t)prev * HID + d], a);
          else agg[(size_t)prev * HID + d] = a;
          firstSeg = false;
        }
        a = 0.f;
        prev = node;
      }
      if (node >= 0) {
        float v = msg[sl * 130 + d] + h[(size_t)s_src[sl] * HID + d];
        a += fmaxf(v, 0.f);
      }
    }
    if (prev >= 0) atomicAdd(&agg[(size_t)prev * HID + d], a);
  }
}

// ======== node MLP via split-bf16 MFMA ========
__global__ __launch_bounds__(256) void mlp_mfma(
    const float* __restrict__ h, const float* __restrict__ agg,
    const unsigned short* __restrict__ wl,
    const float* __restrict__ b1, const float* __restrict__ b2,
    float* __restrict__ hout) {
  __shared__ unsigned short lds[40960];  // 80 KB
  unsigned short* sAh = lds;
  unsigned short* sAl = lds + 4096;
  unsigned short* sBh = lds + 8192;
  unsigned short* sBl = lds + 12288;
  unsigned short* t1h = lds;
  unsigned short* t1l = lds + 16384;
  unsigned short* sB2h = lds + 32768;
  unsigned short* sB2l = lds + 36864;
  const unsigned short* w1h = wl;
  const unsigned short* w1l = wl + 16384;
  const unsigned short* w2h = wl + 32768;
  const unsigned short* w2l = wl + 49152;
  int tid = threadIdx.x, lane = tid & 63, wave = tid >> 6;
  int wm = wave & 1, wn = wave >> 1;
  int mbase = blockIdx.x * 128;
  const f32x4 zf = {0.f, 0.f, 0.f, 0.f};

  f32x4 acc[4][4];
#pragma unroll
  for (int a = 0; a < 4; ++a)
#pragma unroll
    for (int bq = 0; bq < 4; ++bq) acc[a][bq] = zf;

  for (int c = 0; c < 4; ++c) {
    __syncthreads();
#pragma unroll
    for (int it = 0; it < 4; ++it) {
      int idx = it * 256 + tid;
      int m = idx >> 3, k4 = (idx & 7) * 4;
      int row = mbase + m; if (row >= N_NODES) row = N_NODES - 1;
      size_t g = (size_t)row * HID + c * 32 + k4;
      float4 hv = *(const float4*)(h + g);
      float4 av = *(const float4*)(agg + g);
      float z0 = hv.x + av.x, z1 = hv.y + av.y, z2 = hv.z + av.z, z3 = hv.w + av.w;
      unsigned short h0 = f2bf(z0), h1 = f2bf(z1), h2 = f2bf(z2), h3 = f2bf(z3);
      int slot = ((m >> 4) * 4 + (k4 >> 3)) * 16 + (m & 15);
      int off = slot * 8 + (k4 & 7);
      short4v ph = {(short)h0, (short)h1, (short)h2, (short)h3};
      short4v pl = {(short)f2bf(z0 - bf2f(h0)), (short)f2bf(z1 - bf2f(h1)),
                    (short)f2bf(z2 - bf2f(h2)), (short)f2bf(z3 - bf2f(h3))};
      *(short4v*)(sAh + off) = ph;
      *(short4v*)(sAl + off) = pl;
    }
#pragma unroll
    for (int it = 0; it < 2; ++it) {
      int s = it * 256 + tid;
      int ntile = s >> 6, kgrp = (s >> 4) & 3, nrow = s & 15;
      int goff = (ntile * 16 + nrow) * 128 + c * 32 + kgrp * 8;
      *(short8*)(sBh + s * 8) = *(const short8*)(w1h + goff);
      *(short8*)(sBl + s * 8) = *(const short8*)(w1l + goff);
    }
    __syncthreads();
    short8 ah[4], al[4], bh[4], bl[4];
#pragma unroll
    for (int mt = 0; mt < 4; ++mt) {
      ah[mt] = *(short8*)(sAh + ((wm * 4 + mt) * 64 + lane) * 8);
      al[mt] = *(short8*)(sAl + ((wm * 4 + mt) * 64 + lane) * 8);
    }
#pragma unroll
    for (int nt = 0; nt < 4; ++nt) {
      bh[nt] = *(short8*)(sBh + ((wn * 4 + nt) * 64 + lane) * 8);
      bl[nt] = *(short8*)(sBl + ((wn * 4 + nt) * 64 + lane) * 8);
    }
#pragma unroll
    for (int mt = 0; mt < 4; ++mt)
#pragma unroll
      for (int nt = 0; nt < 4; ++nt) {
        acc[mt][nt] = MFMA16(ah[mt], bh[nt], acc[mt][nt]);
        acc[mt][nt] = MFMA16(ah[mt], bl[nt], acc[mt][nt]);
        acc[mt][nt] = MFMA16(al[mt], bh[nt], acc[mt][nt]);
      }
  }
  __syncthreads();
  int q = lane >> 4, r = lane & 15;
#pragma unroll
  for (int nt = 0; nt < 4; ++nt) {
    int n = wn * 64 + nt * 16 + r;
    float b1v = b1[n];
    int kgrp = n >> 3, jj = n & 7;
#pragma unroll
    for (int mt = 0; mt < 4; ++mt) {
      int mtg = wm * 4 + mt;
#pragma unroll
      for (int i2 = 0; i2 < 4; ++i2) {
        int mrow = q * 4 + i2;
        float val = fmaxf(acc[mt][nt][i2] + b1v, 0.f);
        unsigned short hi = f2bf(val);
        int idx = ((mtg * 16 + kgrp) * 16 + mrow) * 8 + jj;
        t1h[idx] = hi;
        t1l[idx] = f2bf(val - bf2f(hi));
      }
    }
  }

  f32x4 acc2[4][4];
#pragma unroll
  for (int a = 0; a < 4; ++a)
#pragma unroll
    for (int bq = 0; bq < 4; ++bq) acc2[a][bq] = zf;

  for (int kc = 0; kc < 4; ++kc) {
    __syncthreads();
#pragma unroll
    for (int it = 0; it < 2; ++it) {
      int s = it * 256 + tid;
      int ntile = s >> 6, kgrp = (s >> 4) & 3, nrow = s & 15;
      int goff = (ntile * 16 + nrow) * 128 + kc * 32 + kgrp * 8;
      *(short8*)(sB2h + s * 8) = *(const short8*)(w2h + goff);
      *(short8*)(sB2l + s * 8) = *(const short8*)(w2l + goff);
    }
    __syncthreads();
    short8 ah[4], al[4], bh[4], bl[4];
#pragma unroll
    for (int mt = 0; mt < 4; ++mt) {
      int mtg = wm * 4 + mt;
      int idx = ((mtg * 16 + kc * 4 + q) * 16 + r) * 8;
      ah[mt] = *(short8*)(t1h + idx);
      al[mt] = *(short8*)(t1l + idx);
    }
#pragma unroll
    for (int nt = 0; nt < 4; ++nt) {
      bh[nt] = *(short8*)(sB2h + ((wn * 4 + nt) * 64 + lane) * 8);
      bl[nt] = *(short8*)(sB2l + ((wn * 4 + nt) * 64 + lane) * 8);
    }
#pragma unroll
    for (int mt = 0; mt < 4; ++mt)
#pragma unroll
      for (int nt = 0; nt < 4; ++nt) {
        acc2[mt][nt] = MFMA16(ah[mt], bh[nt], acc2[mt][nt]);
        acc2[mt][nt] = MFMA16(ah[mt], bl[nt], acc2[mt][nt]);
        acc2[mt][nt] = MFMA16(al[mt], bh[nt], acc2[mt][nt]);
      }
  }
#pragma unroll
  for (int nt = 0; nt < 4; ++nt) {
    int n = wn * 64 + nt * 16 + r;
    float b2v = b2[n];
#pragma unroll
    for (int mt = 0; mt < 4; ++mt) {
      int mtg = wm * 4 + mt;
#pragma unroll
      for (int i2 = 0; i2 < 4; ++i2) {
        int row = mbase + mtg * 16 + q * 4 + i2;
        if (row < N_NODES)
          hout[(size_t)row * HID + n] = fmaxf(acc2[mt][nt][i2] + b2v, 0.f);
      }
    }
  }
}

// ======== classifier via bf16 MFMA ========
__global__ __launch_bounds__(256) void cls_mfma(
    const float* __restrict__ h, const float* __restrict__ ea,
    const int* __restrict__ src, const int* __restrict__ dst,
    const unsigned short* __restrict__ w1t, const unsigned short* __restrict__ w2t,
    const float* __restrict__ b1, const float* __restrict__ b2,
    float* __restrict__ out) {
  __shared__ unsigned short lds[20480];  // 40 KB
  unsigned short* sA = lds;
  unsigned short* sB = lds + 4096;
  unsigned short* t1 = lds;
  unsigned short* sB2 = lds + 16384;
  __shared__ int sidx[256];
  int tid = threadIdx.x, lane = tid & 63, wave = tid >> 6;
  int wm = wave & 1, wn = wave >> 1;
  int ebase = blockIdx.x * 128;
  const f32x4 zf = {0.f, 0.f, 0.f, 0.f};

  {
    int e0 = ebase + (tid & 127);
    if (e0 >= N_EDGES) e0 = N_EDGES - 1;
    sidx[tid] = (tid < 128 ? src : dst)[e0];
  }

  f32x4 acc[4][4];
#pragma unroll
  for (int a = 0; a < 4; ++a)
#pragma unroll
    for (int bq = 0; bq < 4; ++bq) acc[a][bq] = zf;

  for (int c = 0; c < 9; ++c) {
    __syncthreads();
#pragma unroll
    for (int it = 0; it < 4; ++it) {
      int idx = it * 256 + tid;
      int m = idx >> 3, k4 = (idx & 7) * 4;
      const float* rp;
      if (c < 4)      rp = h + (size_t)sidx[m] * HID + c * 32 + k4;
      else if (c < 8) rp = h + (size_t)sidx[128 + m] * HID + (c - 4) * 32 + k4;
      else {
        int e8 = ebase + m; if (e8 >= N_EDGES) e8 = N_EDGES - 1;
        rp = ea + (size_t)e8 * EDGE_DIM + k4;
      }
      float4 v = *(const float4*)rp;
      int slot = ((m >> 4) * 4 + (k4 >> 3)) * 16 + (m & 15);
      short4v pk = {(short)f2bf(v.x), (short)f2bf(v.y), (short)f2bf(v.z), (short)f2bf(v.w)};
      *(short4v*)(sA + slot * 8 + (k4 & 7)) = pk;
    }
#pragma unroll
    for (int it = 0; it < 2; ++it) {
      int s = it * 256 + tid;
      int ntile = s >> 6, kgrp = (s >> 4) & 3, nrow = s & 15;
      *(short8*)(sB + s * 8) = *(const short8*)(w1t + (ntile * 16 + nrow) * 288 + c * 32 + kgrp * 8);
    }
    __syncthreads();
    short8 af[4], bfv[4];
#pragma unroll
    for (int mt = 0; mt < 4; ++mt)
      af[mt] = *(short8*)(sA + ((wm * 4 + mt) * 64 + lane) * 8);
#pragma unroll
    for (int nt = 0; nt < 4; ++nt)
      bfv[nt] = *(short8*)(sB + ((wn * 4 + nt) * 64 + lane) * 8);
#pragma unroll
    for (int mt = 0; mt < 4; ++mt)
#pragma unroll
      for (int nt = 0; nt < 4; ++nt)
        acc[mt][nt] = MFMA16(af[mt], bfv[nt], acc[mt][nt]);
  }
  __syncthreads();
  int q = lane >> 4, r = lane & 15;
#pragma unroll
  for (int nt = 0; nt < 4; ++nt) {
    int n = wn * 64 + nt * 16 + r;
    float b1v = b1[n];
    int kgrp = n >> 3, jj = n & 7;
#pragma unroll
    for (int mt = 0; mt < 4; ++mt) {
      int mtg = wm * 4 + mt;
#pragma unroll
      for (int i2 = 0; i2 < 4; ++i2) {
        int mrow = q * 4 + i2;
        float val = fmaxf(acc[mt][nt][i2] + b1v, 0.f);
        t1[((mtg * 16 + kgrp) * 16 + mrow) * 8 + jj] = f2bf(val);
      }
    }
  }
#pragma unroll
  for (int it = 0; it < 2; ++it) {
    int s = it * 256 + tid;
    int ntile = s >> 8, kgrp = (s >> 4) & 15, nrow = s & 15;
    *(short8*)(sB2 + s * 8) = *(const short8*)(w2t + (ntile * 16 + nrow) * 128 + kgrp * 8);
  }
  __syncthreads();

  f32x4 acc2[2][2];
  acc2[0][0] = zf; acc2[0][1] = zf; acc2[1][0] = zf; acc2[1][1] = zf;
#pragma unroll
  for (int kc = 0; kc < 4; ++kc) {
    short8 a0 = *(short8*)(t1 + (((wave * 2 + 0) * 16 + kc * 4 + q) * 16 + r) * 8);
    short8 a1 = *(short8*)(t1 + (((wave * 2 + 1) * 16 + kc * 4 + q) * 16 + r) * 8);
    short8 b0 = *(short8*)(sB2 + ((0 * 16 + kc * 4 + q) * 16 + r) * 8);
    short8 b1f = *(short8*)(sB2 + ((1 * 16 + kc * 4 + q) * 16 + r) * 8);
    acc2[0][0] = MFMA16(a0, b0, acc2[0][0]);
    acc2[0][1] = MFMA16(a0, b1f, acc2[0][1]);
    acc2[1][0] = MFMA16(a1, b0, acc2[1][0]);
    acc2[1][1] = MFMA16(a1, b1f, acc2[1][1]);
  }
#pragma unroll
  for (int nt2 = 0; nt2 < 2; ++nt2) {
    int n = nt2 * 16 + r;
    float b2v = (n < OUT_DIM) ? b2[n] : 0.f;
#pragma unroll
    for (int mt2 = 0; mt2 < 2; ++mt2) {
      int mtg = wave * 2 + mt2;
#pragma unroll
      for (int i2 = 0; i2 < 4; ++i2) {
        int e = ebase + mtg * 16 + q * 4 + i2;
        if (n < OUT_DIM && e < N_EDGES)
          out[(size_t)e * OUT_DIM + n] = acc2[mt2][nt2][i2] + b2v;
      }
    }
  }
}

extern "C" void kernel_launch(void* const* d_in, const int* in_sizes, int n_in,
                              void* d_out, int out_size, void* d_ws, size_t ws_size,
                              hipStream_t stream) {
  const float* x = (const float*)d_in[0];
  const int* ei = (const int*)d_in[1];
  const float* ea = (const float*)d_in[2];
  const float* lin1_w = (const float*)d_in[3];
  const float* lin1_b = (const float*)d_in[4];
  const int* src = ei;
  const int* dst = ei + N_EDGES;

  const size_t NH = (size_t)N_NODES * HID;
  float* bufA = (float*)d_ws;
  float* bufB = bufA + NH;
  int* ibase = (int*)(bufB + NH);
  int* rowptr = ibase;                 // N_NODES+1
  int* cur = ibase + 100004;           // N_NODES
  int* counts = ibase + 200004;        // N_NODES
  int* perm = ibase + 300004;          // N_EDGES
  int* partial = ibase + 900004;       // 128
  int* partialScan = ibase + 900132;   // 128
  unsigned short* wbase = (unsigned short*)((((uintptr_t)d_ws + ws_size) - (size_t)W_TOTAL * 2) & ~(uintptr_t)255);

  prep_weights<<<(151552 + 255) / 256, 256, 0, stream>>>(
      (const float*)d_in[23], (const float*)d_in[25],
      (const float*)d_in[7], (const float*)d_in[9],
      (const float*)d_in[13], (const float*)d_in[15],
      (const float*)d_in[19], (const float*)d_in[21],
      (const float*)d_in[5], (const float*)d_in[11], (const float*)d_in[17],
      wbase);

  lin1_kernel<<<(N_NODES + 63) / 64, 256, 0, stream>>>(x, lin1_w, lin1_b, bufA);

  // ---- CSR build (once) ----
  hipMemsetAsync(counts, 0, N_NODES * sizeof(int), stream);
  hist_kernel<<<(N_EDGES + 255) / 256, 256, 0, stream>>>(dst, counts);
  scan_partial<<<SCAN_BLK, 256, 0, stream>>>(counts, partial);
  scan_sums<<<1, 64, 0, stream>>>(partial, partialScan, rowptr);
  scan_final<<<SCAN_BLK, 256, 0, stream>>>(counts, partialScan, rowptr, cur);
  scatter_kernel<<<(N_EDGES + 255) / 256, 256, 0, stream>>>(dst, cur, perm);

  float* hcur = bufA;
  float* aux = bufB;
  for (int c = 0; c < 3; ++c) {
    const float* eb = (const float*)d_in[5 + c * 6 + 1];
    const float* b1 = (const float*)d_in[5 + c * 6 + 3];
    const float* b2 = (const float*)d_in[5 + c * 6 + 5];
    hipMemsetAsync(aux, 0, NH * sizeof(float), stream);
    msg_agg_kernel<<<(N_EDGES + 127) / 128, 256, 0, stream>>>(
        hcur, ea, src, dst, perm, wbase + OFF_EWF(c), eb, aux);
    mlp_mfma<<<(N_NODES + 127) / 128, 256, 0, stream>>>(
        hcur, aux, wbase + OFF_LAYER(c), b1, b2, aux);
    float* tmp = hcur; hcur = aux; aux = tmp;
  }

  const float* cb1 = (const float*)d_in[24];
  const float* cb2 = (const float*)d_in[26];
  cls_mfma<<<(N_EDGES + 127) / 128, 256, 0, stream>>>(
      hcur, ea, src, dst, wbase + OFF_CW1T, wbase + OFF_CW2T, cb1, cb2, (float*)d_out);
}